// Round 1
// baseline (769.259 us; speedup 1.0000x reference)
//
#include <hip/hip_runtime.h>
#include <math.h>

#define DIM   4096
#define DIM4  (DIM / 4)          // float4 per row
#define NELEM4 (DIM * DIM / 4)   // total float4
#define NITER 20
#define EPSF  1e-10f
#define NRG   16                 // row groups for column reduction

// ---------------- wave / block reduction helpers ----------------
__device__ __forceinline__ float waveMax(float v) {
#pragma unroll
    for (int o = 32; o > 0; o >>= 1) v = fmaxf(v, __shfl_down(v, o, 64));
    return v;
}
__device__ __forceinline__ float waveSum(float v) {
#pragma unroll
    for (int o = 32; o > 0; o >>= 1) v += __shfl_down(v, o, 64);
    return v;
}

// ---------------- init: L0 = logits + gumbel(noise); c = 0 ----------------
__global__ __launch_bounds__(256) void init_k(const float* __restrict__ logits,
                                              const float* __restrict__ noise,
                                              float* __restrict__ L0,
                                              float* __restrict__ c) {
    int idx = blockIdx.x * blockDim.x + threadIdx.x;
    int stride = gridDim.x * blockDim.x;
    const float4* l4 = (const float4*)logits;
    const float4* n4 = (const float4*)noise;
    float4* o4 = (float4*)L0;
    for (int p = idx; p < NELEM4; p += stride) {
        float4 l = l4[p];
        float4 u = n4[p];
        float4 o;
        // g = -log(-log(u+eps)+eps); la = l + g
        o.x = l.x - logf(-logf(u.x + EPSF) + EPSF);
        o.y = l.y - logf(-logf(u.y + EPSF) + EPSF);
        o.z = l.z - logf(-logf(u.z + EPSF) + EPSF);
        o.w = l.w - logf(-logf(u.w + EPSF) + EPSF);
        o4[p] = o;
    }
    if (idx < DIM) c[idx] = 0.0f;
}

// ---------------- row LSE: r[i] = LSE_j(L0[i][j] - c[j]) ----------------
__global__ __launch_bounds__(256) void row_lse(const float* __restrict__ L0,
                                               const float* __restrict__ c,
                                               float* __restrict__ r) {
    __shared__ float red[8];
    const int row = blockIdx.x;
    const int t = threadIdx.x;
    const float4* a4 = (const float4*)(L0 + (size_t)row * DIM);
    const float4* c4 = (const float4*)c;
    float v[16];
    float m = -INFINITY;
#pragma unroll
    for (int k = 0; k < 4; ++k) {
        float4 a  = a4[t + k * 256];
        float4 cc = c4[t + k * 256];
        v[4 * k + 0] = a.x - cc.x;
        v[4 * k + 1] = a.y - cc.y;
        v[4 * k + 2] = a.z - cc.z;
        v[4 * k + 3] = a.w - cc.w;
        m = fmaxf(m, fmaxf(fmaxf(v[4 * k], v[4 * k + 1]), fmaxf(v[4 * k + 2], v[4 * k + 3])));
    }
    m = waveMax(m);
    const int lane = t & 63, wid = t >> 6;
    if (lane == 0) red[wid] = m;
    __syncthreads();
    const float bm = fmaxf(fmaxf(red[0], red[1]), fmaxf(red[2], red[3]));
    float s = 0.0f;
#pragma unroll
    for (int q = 0; q < 16; ++q) s += __expf(v[q] - bm);
    s = waveSum(s);
    if (lane == 0) red[4 + wid] = s;   // disjoint from red[0..3]; no extra sync needed
    __syncthreads();
    if (t == 0) {
        float bs = red[4] + red[5] + red[6] + red[7];
        r[row] = bm + logf(bs);
    }
}

// ---------------- col LSE stage 1: per-(col, row-chunk) online partials ----------------
__global__ __launch_bounds__(1024) void col_partial(const float* __restrict__ L0,
                                                    const float* __restrict__ r,
                                                    float2* __restrict__ part) {
    __shared__ float sr[256];
    __shared__ float smm[1024];
    __shared__ float sms[1024];
    const int g = blockIdx.x;       // col group: 256 cols
    const int h = blockIdx.y;       // row group: 256 rows
    const int tc = threadIdx.x & 255;
    const int lane = threadIdx.x >> 8;  // 0..3
    if (threadIdx.x < 256) sr[threadIdx.x] = r[h * 256 + threadIdx.x];
    __syncthreads();
    const int j = g * 256 + tc;
    float m = -INFINITY, s = 0.0f;
#pragma unroll 4
    for (int k = 0; k < 64; ++k) {
        int ii = k * 4 + lane;
        float v = L0[(size_t)(h * 256 + ii) * DIM + j] - sr[ii];
        float nm = fmaxf(m, v);
        s = s * __expf(m - nm) + __expf(v - nm);
        m = nm;
    }
    smm[threadIdx.x] = m;
    sms[threadIdx.x] = s;
    __syncthreads();
    if (threadIdx.x < 256) {
        float m0 = smm[tc], m1 = smm[tc + 256], m2 = smm[tc + 512], m3 = smm[tc + 768];
        float M = fmaxf(fmaxf(m0, m1), fmaxf(m2, m3));
        float S = sms[tc] * __expf(m0 - M) + sms[tc + 256] * __expf(m1 - M) +
                  sms[tc + 512] * __expf(m2 - M) + sms[tc + 768] * __expf(m3 - M);
        part[h * DIM + j] = make_float2(M, S);
    }
}

// ---------------- col LSE stage 2: combine NRG partials -> c[j] ----------------
__global__ __launch_bounds__(256) void col_combine(const float2* __restrict__ part,
                                                   float* __restrict__ c) {
    int j = blockIdx.x * 256 + threadIdx.x;
    float pm[NRG], ps[NRG];
    float M = -INFINITY;
#pragma unroll
    for (int h = 0; h < NRG; ++h) {
        float2 p = part[h * DIM + j];
        pm[h] = p.x;
        ps[h] = p.y;
        M = fmaxf(M, p.x);
    }
    float S = 0.0f;
#pragma unroll
    for (int h = 0; h < NRG; ++h) S += ps[h] * __expf(pm[h] - M);
    c[j] = M + logf(S);
}

// ---------------- final: out = exp(L0 - r - c) in place ----------------
__global__ __launch_bounds__(256) void final_exp(float* __restrict__ L0,
                                                 const float* __restrict__ r,
                                                 const float* __restrict__ c) {
    const float4* c4 = (const float4*)c;
    float4* a4 = (float4*)L0;
    int idx = blockIdx.x * blockDim.x + threadIdx.x;
    int stride = gridDim.x * blockDim.x;
    for (int p = idx; p < NELEM4; p += stride) {
        int i  = p >> 10;      // row (1024 float4 per row)
        int j4 = p & 1023;
        float4 a = a4[p];
        float rr = r[i];
        float4 cc = c4[j4];
        a.x = __expf(a.x - rr - cc.x);
        a.y = __expf(a.y - rr - cc.y);
        a.z = __expf(a.z - rr - cc.z);
        a.w = __expf(a.w - rr - cc.w);
        a4[p] = a;
    }
}

extern "C" void kernel_launch(void* const* d_in, const int* in_sizes, int n_in,
                              void* d_out, int out_size, void* d_ws, size_t ws_size,
                              hipStream_t stream) {
    const float* logits = (const float*)d_in[0];
    const float* noise  = (const float*)d_in[1];
    float* out = (float*)d_out;          // doubles as L0 scratch until final_exp
    float* ws  = (float*)d_ws;
    float*  r    = ws;                   // DIM floats
    float*  c    = ws + DIM;             // DIM floats
    float2* part = (float2*)(ws + 2 * DIM);  // NRG*DIM float2 = 512 KiB

    init_k<<<4096, 256, 0, stream>>>(logits, noise, out, c);
    for (int t = 0; t < NITER; ++t) {
        row_lse<<<DIM, 256, 0, stream>>>(out, c, r);
        col_partial<<<dim3(16, 16), 1024, 0, stream>>>(out, r, part);
        col_combine<<<16, 256, 0, stream>>>(part, c);
    }
    final_exp<<<4096, 256, 0, stream>>>(out, r, c);
}